// Round 15
// baseline (227.910 us; speedup 1.0000x reference)
//
#include <hip/hip_runtime.h>

#define NN 50000
#define NE 640000
#define NBK 196      // buckets of 256 nodes
#define CHUNK 2560   // edges per block in bucket passes: NE/CHUNK = 250

typedef __attribute__((ext_vector_type(8))) short s8v;
typedef __attribute__((ext_vector_type(4))) float f4v;

__device__ __forceinline__ unsigned short f2bf(float x) {  // RNE f32->bf16
  unsigned int u = __float_as_uint(x);
  return (unsigned short)((u + 0x7fffu + ((u >> 16) & 1u)) >> 16);
}
__device__ __forceinline__ float bfval(unsigned short h) {
  return __uint_as_float((unsigned int)h << 16);
}
__device__ __forceinline__ float2 bfpair(unsigned int u) {
  float2 r;
  r.x = __uint_as_float((u & 0xffffu) << 16);
  r.y = __uint_as_float(u & 0xffff0000u);
  return r;
}

// async global->LDS, 16B per lane; LDS dest = wave-uniform base + lane*16
__device__ __forceinline__ void gload_lds16(const void* g, void* l) {
  __builtin_amdgcn_global_load_lds(
      (const __attribute__((address_space(1))) void*)g,
      (__attribute__((address_space(3))) void*)l, 16, 0, 0);
}

// ---------------- Bucketed CSR (dest-keyed) build ----------------

__global__ __launch_bounds__(256) void bucket_count_kernel(const int* __restrict__ col,
                                                           int* __restrict__ bcnt) {
  __shared__ int h[NBK];
  const int tid = threadIdx.x;
  for (int i = tid; i < NBK; i += 256) h[i] = 0;
  __syncthreads();
  const int base = blockIdx.x * CHUNK;
  for (int i = tid; i < CHUNK; i += 256) atomicAdd(&h[col[base + i] >> 8], 1);
  __syncthreads();
  for (int i = tid; i < NBK; i += 256)
    if (h[i]) atomicAdd(&bcnt[i], h[i]);
}

__global__ __launch_bounds__(256) void scan196_kernel(const int* __restrict__ bcnt,
                                                      int* __restrict__ boff) {
  __shared__ int s[256];
  const int tid = threadIdx.x;
  int v = (tid < NBK) ? bcnt[tid] : 0;
  s[tid] = v;
  __syncthreads();
  for (int off = 1; off < 256; off <<= 1) {
    int u = (tid >= off) ? s[tid - off] : 0;
    __syncthreads();
    s[tid] += u;
    __syncthreads();
  }
  if (tid <= NBK) boff[tid] = (tid == 0) ? 0 : s[tid - 1];
}

__global__ __launch_bounds__(256) void bucket_scatter_kernel(
    const int* __restrict__ row, const int* __restrict__ col,
    const int* __restrict__ boff, int* __restrict__ bfill,
    unsigned int* __restrict__ ebuf) {
  __shared__ int h[NBK], gst[NBK], h2[NBK];
  const int tid = threadIdx.x;
  for (int i = tid; i < NBK; i += 256) { h[i] = 0; h2[i] = 0; }
  __syncthreads();
  const int base = blockIdx.x * CHUNK;
  for (int i = tid; i < CHUNK; i += 256) atomicAdd(&h[col[base + i] >> 8], 1);
  __syncthreads();
  for (int i = tid; i < NBK; i += 256) gst[i] = h[i] ? atomicAdd(&bfill[i], h[i]) : 0;
  __syncthreads();
  for (int i = tid; i < CHUNK; i += 256) {
    int c = col[base + i];
    int b = c >> 8;
    int r = atomicAdd(&h2[b], 1);
    unsigned int packed = ((unsigned int)row[base + i] << 8) | (unsigned int)(c & 255);
    ebuf[boff[b] + gst[b] + r] = packed;
  }
}

__global__ __launch_bounds__(256) void bucket_build_kernel(
    const unsigned int* __restrict__ ebuf, const int* __restrict__ boff,
    int* __restrict__ row_ptr, float* __restrict__ dis, int* __restrict__ csr, int n) {
  __shared__ int cnt[256], c2[256], lbase[256], wsum[4];
  const int tid = threadIdx.x;
  const int b = blockIdx.x;
  const int s0 = boff[b], s1 = boff[b + 1];
  cnt[tid] = 0;
  c2[tid] = 0;
  __syncthreads();
  for (int i = s0 + tid; i < s1; i += 256) atomicAdd(&cnt[ebuf[i] & 255], 1);
  __syncthreads();

  const int lane = tid & 63, w = tid >> 6;
  int c = cnt[tid];
  int inc = c;
#pragma unroll
  for (int off = 1; off < 64; off <<= 1) {
    int u = __shfl_up(inc, off);
    if (lane >= off) inc += u;
  }
  if (lane == 63) wsum[w] = inc;
  __syncthreads();
  int wo = 0;
  for (int i = 0; i < w; ++i) wo += wsum[i];
  const int excl = wo + inc - c;

  const int node = b * 256 + tid;
  if (node <= n) row_ptr[node] = s0 + excl;
  if (node < n) dis[node] = rsqrtf((float)(c + 1));
  lbase[tid] = s0 + excl;
  __syncthreads();

  for (int i = s0 + tid; i < s1; i += 256) {
    unsigned int p = ebuf[i];
    int dl = p & 255;
    int r = atomicAdd(&c2[dl], 1);
    csr[lbase[dl] + r] = (int)(p >> 8);
  }
}

// ---------------- W prep: transpose + split f32 -> bf16 hi/lo ----------------

__global__ __launch_bounds__(256) void wprep_kernel(
    const float* __restrict__ W1, const float* __restrict__ W2,
    unsigned short* __restrict__ wt1h, unsigned short* __restrict__ wt1l,
    unsigned short* __restrict__ wt2h, unsigned short* __restrict__ wt2l) {
  int idx = blockIdx.x * 256 + threadIdx.x;  // 0..24575
  if (idx < 16384) {
    int c = idx >> 7, k = idx & 127;
    float w = W1[k * 128 + c];
    unsigned short h = f2bf(w);
    wt1h[idx] = h;
    wt1l[idx] = f2bf(w - bfval(h));
  } else if (idx < 24576) {
    int i2 = idx - 16384;
    int c = i2 >> 7, k = i2 & 127;
    float w = W2[k * 64 + c];
    unsigned short h = f2bf(w);
    wt2h[i2] = h;
    wt2l[i2] = f2bf(w - bfval(h));
  }
}

// ---------------- MFMA GEMM: 2-phase dbuf global_load_lds (guide T3-minimum) ----------------
// out[r][c] = dis[r] * sum_{k<128} A[r][k] * Wt[c][k]
// Per kt: STAGE(buf^1, kt+1) issued BEFORE compute(buf); ONE __syncthreads per kt
// (its vmcnt(0) drain is the required wait for tile kt+1; prefetch overlaps compute kt).
// `rep` repeats the whole body (attribution duplicates; main path rep=1).

template <int BM, int NCOLS, bool AF32, bool OUTBF16>
__global__ __launch_bounds__(256) void gemm_mfma_kernel(
    const void* __restrict__ Av, const unsigned short* __restrict__ Bth,
    const unsigned short* __restrict__ Btl, const float* __restrict__ dis,
    void* __restrict__ outv, int M, int rep) {
  constexpr int WCOL = NCOLS / 64;
  constexpr int WROW = 4 / WCOL;
  constexpr int RG = BM / (WROW * 16);
  constexpr int A_BYTES = BM * 32 * (AF32 ? 4 : 2);
  constexpr int B_BYTES = NCOLS * 32 * 2;
  constexpr int TILE_BYTES = A_BYTES + 2 * B_BYTES;
  constexpr int STAGE_BYTES = 2 * TILE_BYTES;
  constexpr int EPI_PITCH = OUTBF16 ? (NCOLS + 8) : (NCOLS + 4);
  constexpr int EPI_BYTES = BM * EPI_PITCH * (OUTBF16 ? 2 : 4);
  constexpr int SMEM_BYTES = STAGE_BYTES > EPI_BYTES ? STAGE_BYTES : EPI_BYTES;

  __shared__ __align__(16) unsigned char smem[SMEM_BYTES];

  const int t = threadIdx.x;
  const int lane = t & 63;
  const int l15 = lane & 15;
  const int lg = lane >> 4;
  const int wv = t >> 6;
  const int wr = wv % WROW;
  const int wc = wv / WROW;
  const int rb = blockIdx.x * BM;

  auto stage = [&](int kt, int buf) {
    unsigned char* base = smem + buf * TILE_BYTES;
    if constexpr (AF32) {
      constexpr int CPW = (BM * 128 / 1024) / 4;  // gload calls per wave
#pragma unroll
      for (int j = 0; j < CPW; ++j) {
        int callr = (wv * CPW + j) * 8;
        int gr = min(rb + callr + (lane >> 3), M - 1);
        const float* gp = (const float*)Av + (size_t)gr * 128 + kt * 32 + (lane & 7) * 4;
        gload_lds16(gp, base + callr * 128);
      }
    } else {
      constexpr int CPW = (BM * 64 / 1024) / 4;
#pragma unroll
      for (int j = 0; j < CPW; ++j) {
        int callr = (wv * CPW + j) * 16;
        int gr = min(rb + callr + (lane >> 2), M - 1);
        const unsigned short* gp =
            (const unsigned short*)Av + (size_t)gr * 128 + kt * 32 + (lane & 3) * 8;
        gload_lds16(gp, base + callr * 64);
      }
    }
    {
      constexpr int CPW = (NCOLS * 64 / 1024) / 4;
#pragma unroll
      for (int j = 0; j < CPW; ++j) {
        int callr = (wv * CPW + j) * 16;
        int r = callr + (lane >> 2);
        size_t goff = (size_t)r * 128 + kt * 32 + (lane & 3) * 8;
        gload_lds16(Bth + goff, base + A_BYTES + callr * 64);
        gload_lds16(Btl + goff, base + A_BYTES + B_BYTES + callr * 64);
      }
    }
  };

  for (int it = 0; it < rep; ++it) {
    f4v acc[RG][4];
#pragma unroll
    for (int i = 0; i < RG; ++i)
#pragma unroll
      for (int j = 0; j < 4; ++j) acc[i][j] = (f4v){0.f, 0.f, 0.f, 0.f};

    stage(0, 0);
    __syncthreads();  // vmcnt(0) drain -> tile 0 landed

#pragma unroll
    for (int kt = 0; kt < 4; ++kt) {
      const int buf = kt & 1;
      if (kt < 3) stage(kt + 1, buf ^ 1);  // async prefetch; overlaps compute below

      const unsigned char* tb = smem + buf * TILE_BYTES;
      s8v afh[RG], afl[RG];
#pragma unroll
      for (int rg = 0; rg < RG; ++rg) {
        int row = wr * (RG * 16) + rg * 16 + l15;
        if constexpr (AF32) {
          const float* ap = (const float*)tb + row * 32 + lg * 8;
          float4 x0 = *reinterpret_cast<const float4*>(ap);
          float4 x1 = *reinterpret_cast<const float4*>(ap + 4);
          float f[8] = {x0.x, x0.y, x0.z, x0.w, x1.x, x1.y, x1.z, x1.w};
#pragma unroll
          for (int q = 0; q < 8; ++q) {
            unsigned short hq = f2bf(f[q]);
            afh[rg][q] = (short)hq;
            afl[rg][q] = (short)f2bf(f[q] - bfval(hq));
          }
        } else {
          afh[rg] = *reinterpret_cast<const s8v*>((const unsigned short*)tb + row * 32 + lg * 8);
        }
      }
#pragma unroll
      for (int cg = 0; cg < 4; ++cg) {
        int colr = wc * 64 + cg * 16 + l15;
        s8v bh = *reinterpret_cast<const s8v*>(
            (const unsigned short*)(tb + A_BYTES) + colr * 32 + lg * 8);
        s8v bl = *reinterpret_cast<const s8v*>(
            (const unsigned short*)(tb + A_BYTES + B_BYTES) + colr * 32 + lg * 8);
#pragma unroll
        for (int rg = 0; rg < RG; ++rg) {
          acc[rg][cg] = __builtin_amdgcn_mfma_f32_16x16x32_bf16(afh[rg], bh, acc[rg][cg], 0, 0, 0);
          acc[rg][cg] = __builtin_amdgcn_mfma_f32_16x16x32_bf16(afh[rg], bl, acc[rg][cg], 0, 0, 0);
          if constexpr (AF32)
            acc[rg][cg] = __builtin_amdgcn_mfma_f32_16x16x32_bf16(afl[rg], bh, acc[rg][cg], 0, 0, 0);
        }
      }
      __syncthreads();  // drains vmcnt(0) (tile kt+1 landed) + all waves done reading buf
    }

    // ---- epilogue: scale, stage to LDS, coalesced store ----
    float dv[RG][4];
#pragma unroll
    for (int rg = 0; rg < RG; ++rg)
#pragma unroll
      for (int g = 0; g < 4; ++g) {
        int r = rb + wr * (RG * 16) + rg * 16 + lg * 4 + g;
        dv[rg][g] = (r < M) ? dis[r] : 0.f;
      }

#pragma unroll
    for (int rg = 0; rg < RG; ++rg)
#pragma unroll
      for (int cg = 0; cg < 4; ++cg) {
        int colc = wc * 64 + cg * 16 + l15;
#pragma unroll
        for (int g = 0; g < 4; ++g) {
          int r = wr * (RG * 16) + rg * 16 + lg * 4 + g;  // block-local row
          float o = acc[rg][cg][g] * dv[rg][g];
          if constexpr (OUTBF16)
            ((unsigned short*)smem)[r * EPI_PITCH + colc] = f2bf(o);
          else
            ((float*)smem)[r * EPI_PITCH + colc] = o;
        }
      }
    __syncthreads();

    constexpr int CHR = OUTBF16 ? (NCOLS / 8) : (NCOLS / 4);
#pragma unroll
    for (int itc = 0; itc < BM * CHR / 256; ++itc) {
      int ch = t + itc * 256;
      int r = ch / CHR, cc = ch % CHR;
      if (rb + r < M) {
        if constexpr (OUTBF16) {
          int4 v = *reinterpret_cast<const int4*>(&((unsigned short*)smem)[r * EPI_PITCH + cc * 8]);
          *reinterpret_cast<int4*>(&((unsigned short*)outv)[(size_t)(rb + r) * NCOLS + cc * 8]) = v;
        } else {
          int4 v = *reinterpret_cast<const int4*>(&((float*)smem)[r * EPI_PITCH + cc * 4]);
          *reinterpret_cast<int4*>(&((float*)outv)[(size_t)(rb + r) * NCOLS + cc * 4]) = v;
        }
      }
    }
    __syncthreads();  // epi smem reads done before next rep restages
  }
}

// ---------------- Aggregation (unroll 8, independent accumulators) ----------------

__global__ __launch_bounds__(256) void agg_bf16_kernel(
    const unsigned int* __restrict__ H, const int* __restrict__ row_ptr,
    const int* __restrict__ csr, const float* __restrict__ dis,
    const float* __restrict__ bias, unsigned int* __restrict__ Z, int n, int rep) {
  const int lane = threadIdx.x & 63;
  const int node = blockIdx.x * 4 + (threadIdx.x >> 6);
  if (node >= n) return;

  for (int it = 0; it < rep; ++it) {
    float2 a[8];
    a[0] = bfpair(H[(size_t)node * 64 + lane]);  // self-loop
#pragma unroll
    for (int i = 1; i < 8; ++i) a[i] = make_float2(0.f, 0.f);

    const int s0 = row_ptr[node], s1 = row_ptr[node + 1];
    for (int e = s0; e < s1; e += 64) {
      int m = s1 - e;
      if (m > 64) m = 64;
      int idx = 0;
      if (lane < m) idx = csr[e + lane];
      int j = 0;
      for (; j + 8 <= m; j += 8) {
        int i0 = __shfl(idx, j),     i1 = __shfl(idx, j + 1);
        int i2 = __shfl(idx, j + 2), i3 = __shfl(idx, j + 3);
        int i4 = __shfl(idx, j + 4), i5 = __shfl(idx, j + 5);
        int i6 = __shfl(idx, j + 6), i7 = __shfl(idx, j + 7);
        float2 v0 = bfpair(H[(size_t)i0 * 64 + lane]);
        float2 v1 = bfpair(H[(size_t)i1 * 64 + lane]);
        float2 v2 = bfpair(H[(size_t)i2 * 64 + lane]);
        float2 v3 = bfpair(H[(size_t)i3 * 64 + lane]);
        float2 v4 = bfpair(H[(size_t)i4 * 64 + lane]);
        float2 v5 = bfpair(H[(size_t)i5 * 64 + lane]);
        float2 v6 = bfpair(H[(size_t)i6 * 64 + lane]);
        float2 v7 = bfpair(H[(size_t)i7 * 64 + lane]);
        a[0].x += v0.x; a[0].y += v0.y;  a[1].x += v1.x; a[1].y += v1.y;
        a[2].x += v2.x; a[2].y += v2.y;  a[3].x += v3.x; a[3].y += v3.y;
        a[4].x += v4.x; a[4].y += v4.y;  a[5].x += v5.x; a[5].y += v5.y;
        a[6].x += v6.x; a[6].y += v6.y;  a[7].x += v7.x; a[7].y += v7.y;
      }
      for (; j + 4 <= m; j += 4) {
        int i0 = __shfl(idx, j),     i1 = __shfl(idx, j + 1);
        int i2 = __shfl(idx, j + 2), i3 = __shfl(idx, j + 3);
        float2 v0 = bfpair(H[(size_t)i0 * 64 + lane]);
        float2 v1 = bfpair(H[(size_t)i1 * 64 + lane]);
        float2 v2 = bfpair(H[(size_t)i2 * 64 + lane]);
        float2 v3 = bfpair(H[(size_t)i3 * 64 + lane]);
        a[0].x += v0.x; a[0].y += v0.y;  a[1].x += v1.x; a[1].y += v1.y;
        a[2].x += v2.x; a[2].y += v2.y;  a[3].x += v3.x; a[3].y += v3.y;
      }
      for (; j < m; ++j) {
        float2 v = bfpair(H[(size_t)__shfl(idx, j) * 64 + lane]);
        a[0].x += v.x; a[0].y += v.y;
      }
    }
    const float d = dis[node];
    float2 b = *reinterpret_cast<const float2*>(&bias[lane * 2]);
    float sx = ((a[0].x + a[1].x) + (a[2].x + a[3].x)) + ((a[4].x + a[5].x) + (a[6].x + a[7].x));
    float sy = ((a[0].y + a[1].y) + (a[2].y + a[3].y)) + ((a[4].y + a[5].y) + (a[6].y + a[7].y));
    float ox = fmaxf(sx * d + b.x, 0.f);
    float oy = fmaxf(sy * d + b.y, 0.f);
    Z[(size_t)node * 64 + lane] = (unsigned int)f2bf(ox) | ((unsigned int)f2bf(oy) << 16);
  }
}

__global__ __launch_bounds__(256) void agg_f32_kernel(
    const float* __restrict__ Hs, const int* __restrict__ row_ptr,
    const int* __restrict__ csr, const float* __restrict__ dis,
    const float* __restrict__ bias, float* __restrict__ out, int n) {
  const int lane = threadIdx.x & 63;
  const int node = blockIdx.x * 4 + (threadIdx.x >> 6);
  if (node >= n) return;

  float a[8];
  a[0] = Hs[(size_t)node * 64 + lane];  // self-loop
#pragma unroll
  for (int i = 1; i < 8; ++i) a[i] = 0.f;

  const int s0 = row_ptr[node], s1 = row_ptr[node + 1];
  for (int e = s0; e < s1; e += 64) {
    int m = s1 - e;
    if (m > 64) m = 64;
    int idx = 0;
    if (lane < m) idx = csr[e + lane];
    int j = 0;
    for (; j + 8 <= m; j += 8) {
      int i0 = __shfl(idx, j),     i1 = __shfl(idx, j + 1);
      int i2 = __shfl(idx, j + 2), i3 = __shfl(idx, j + 3);
      int i4 = __shfl(idx, j + 4), i5 = __shfl(idx, j + 5);
      int i6 = __shfl(idx, j + 6), i7 = __shfl(idx, j + 7);
      float v0 = Hs[(size_t)i0 * 64 + lane];
      float v1 = Hs[(size_t)i1 * 64 + lane];
      float v2 = Hs[(size_t)i2 * 64 + lane];
      float v3 = Hs[(size_t)i3 * 64 + lane];
      float v4 = Hs[(size_t)i4 * 64 + lane];
      float v5 = Hs[(size_t)i5 * 64 + lane];
      float v6 = Hs[(size_t)i6 * 64 + lane];
      float v7 = Hs[(size_t)i7 * 64 + lane];
      a[0] += v0; a[1] += v1; a[2] += v2; a[3] += v3;
      a[4] += v4; a[5] += v5; a[6] += v6; a[7] += v7;
    }
    for (; j + 4 <= m; j += 4) {
      int i0 = __shfl(idx, j),     i1 = __shfl(idx, j + 1);
      int i2 = __shfl(idx, j + 2), i3 = __shfl(idx, j + 3);
      float v0 = Hs[(size_t)i0 * 64 + lane];
      float v1 = Hs[(size_t)i1 * 64 + lane];
      float v2 = Hs[(size_t)i2 * 64 + lane];
      float v3 = Hs[(size_t)i3 * 64 + lane];
      a[0] += v0; a[1] += v1; a[2] += v2; a[3] += v3;
    }
    for (; j < m; ++j) a[0] += Hs[(size_t)__shfl(idx, j) * 64 + lane];
  }
  float s = ((a[0] + a[1]) + (a[2] + a[3])) + ((a[4] + a[5]) + (a[6] + a[7]));
  out[(size_t)node * 64 + lane] = s * dis[node] + bias[lane];
}

// ---------------- launch ----------------

extern "C" void kernel_launch(void* const* d_in, const int* in_sizes, int n_in,
                              void* d_out, int out_size, void* d_ws, size_t ws_size,
                              hipStream_t stream) {
  const float* x  = (const float*)d_in[0];
  const int*   ei = (const int*)d_in[1];
  const float* W1 = (const float*)d_in[2];
  const float* b1 = (const float*)d_in[3];
  const float* W2 = (const float*)d_in[4];
  const float* b2 = (const float*)d_in[5];
  float* out = (float*)d_out;

  const int* row = ei;        // source nodes
  const int* col = ei + NE;   // destination nodes

  char* ws = (char*)d_ws;
  size_t off = 0;
  auto alloc = [&](size_t bytes) -> void* {
    off = (off + 255) & ~(size_t)255;
    void* p = ws + off;
    off += bytes;
    return p;
  };

  int* bcnt    = (int*)alloc((size_t)2 * NBK * sizeof(int));  // bcnt | bfill
  int* bfill   = bcnt + NBK;
  int* boff    = (int*)alloc((size_t)(NBK + 1) * sizeof(int));
  unsigned int* ebuf = (unsigned int*)alloc((size_t)NE * sizeof(unsigned int));
  int* row_ptr = (int*)alloc((size_t)(NN + 1) * sizeof(int));
  int* csr     = (int*)alloc((size_t)NE * sizeof(int));
  float* dis   = (float*)alloc((size_t)NN * sizeof(float));
  unsigned short* wt1h = (unsigned short*)alloc((size_t)(2 * 128 * 128 + 2 * 64 * 128) * 2);
  unsigned short* wt1l = wt1h + 128 * 128;
  unsigned short* wt2h = wt1l + 128 * 128;
  unsigned short* wt2l = wt2h + 64 * 128;
  // HT region: bf16 [NN][128] for layer-1 GEMM out, then f32 [NN][64] for layer-2
  unsigned short* HT16 = (unsigned short*)alloc((size_t)NN * 128 * 2);
  float* HT32 = (float*)HT16;
  unsigned int* HTu = (unsigned int*)HT16;
  unsigned short* Z1 = (unsigned short*)alloc((size_t)NN * 128 * 2);
  unsigned int* Z1u = (unsigned int*)Z1;
  // attribution scratch (dup kernels; removed next round)
  unsigned short* HTdup = (unsigned short*)alloc((size_t)NN * 128 * 2);
  unsigned int* Zdup = (unsigned int*)alloc((size_t)NN * 128 * 2);

  hipMemsetAsync(bcnt, 0, (size_t)2 * NBK * sizeof(int), stream);
  wprep_kernel<<<96, 256, 0, stream>>>(W1, W2, wt1h, wt1l, wt2h, wt2l);
  bucket_count_kernel<<<NE / CHUNK, 256, 0, stream>>>(col, bcnt);
  scan196_kernel<<<1, 256, 0, stream>>>(bcnt, boff);
  bucket_scatter_kernel<<<NE / CHUNK, 256, 0, stream>>>(row, col, boff, bfill, ebuf);
  bucket_build_kernel<<<NBK, 256, 0, stream>>>(ebuf, boff, row_ptr, dis, csr, NN);

  const int ga = (NN + 3) / 4;

  // Layer 1: HT16 = bf16( dis .* (X @ W1) )  [NN][128], BM=64 -> 782 blocks
  gemm_mfma_kernel<64, 128, true, true><<<(NN + 63) / 64, 256, 0, stream>>>(
      x, wt1h, wt1l, dis, HT16, NN, 1);
  agg_bf16_kernel<<<ga, 256, 0, stream>>>(HTu, row_ptr, csr, dis, b1, Z1u, NN, 1);

  // Layer 2: HT32 = dis .* (Z1 @ W2)  [NN][64], BM=128 -> 391 blocks
  gemm_mfma_kernel<128, 64, false, false><<<(NN + 127) / 128, 256, 0, stream>>>(
      Z1, wt2h, wt2l, dis, HT32, NN, 1);
  agg_f32_kernel<<<ga, 256, 0, stream>>>(HT32, row_ptr, csr, dis, b2, out, NN);

  // ---- attribution duplicates (deterministic, scratch outputs; after real work) ----
  // rep=4 pushes each dispatch above the 43us harness-fill threshold -> top-5 w/ PMC.
  gemm_mfma_kernel<64, 128, true, true><<<(NN + 63) / 64, 256, 0, stream>>>(
      x, wt1h, wt1l, dis, HTdup, NN, 4);
  agg_bf16_kernel<<<ga, 256, 0, stream>>>(Z1u, row_ptr, csr, dis, b1, Zdup, NN, 4);
}

// Round 16
// 124.052 us; speedup vs baseline: 1.8372x; 1.8372x over previous
//
#include <hip/hip_runtime.h>

#define NN 50000
#define NE 640000
#define NBK 196      // buckets of 256 nodes
#define CHUNK 2560   // edges per block in bucket passes: NE/CHUNK = 250

typedef __attribute__((ext_vector_type(8))) short s8v;
typedef __attribute__((ext_vector_type(4))) float f4v;

__device__ __forceinline__ unsigned short f2bf(float x) {  // RNE f32->bf16
  unsigned int u = __float_as_uint(x);
  return (unsigned short)((u + 0x7fffu + ((u >> 16) & 1u)) >> 16);
}
__device__ __forceinline__ float bfval(unsigned short h) {
  return __uint_as_float((unsigned int)h << 16);
}
__device__ __forceinline__ float2 bfpair(unsigned int u) {
  float2 r;
  r.x = __uint_as_float((u & 0xffffu) << 16);
  r.y = __uint_as_float(u & 0xffff0000u);
  return r;
}

// async global->LDS, 16B per lane; LDS dest = wave-uniform base + lane*16
__device__ __forceinline__ void gload_lds16(const void* g, void* l) {
  __builtin_amdgcn_global_load_lds(
      (const __attribute__((address_space(1))) void*)g,
      (__attribute__((address_space(3))) void*)l, 16, 0, 0);
}

// ---------------- W prep + bcnt|bfill zero (replaces hipMemsetAsync) ----------------
// Blocks 0..95: W transpose/split. Block 96: zero bcnt|bfill (kernel boundary
// orders this before bucket_count -- R11-proven pattern).

__global__ __launch_bounds__(256) void wprep_kernel(
    const float* __restrict__ W1, const float* __restrict__ W2,
    unsigned short* __restrict__ wt1h, unsigned short* __restrict__ wt1l,
    unsigned short* __restrict__ wt2h, unsigned short* __restrict__ wt2l,
    int* __restrict__ bcnt) {
  const int b = blockIdx.x;
  const int t = threadIdx.x;
  if (b == 96) {
    for (int i = t; i < 2 * NBK; i += 256) bcnt[i] = 0;  // bcnt | bfill
    return;
  }
  int idx = b * 256 + t;  // 0..24575
  if (idx < 16384) {
    int c = idx >> 7, k = idx & 127;
    float w = W1[k * 128 + c];
    unsigned short h = f2bf(w);
    wt1h[idx] = h;
    wt1l[idx] = f2bf(w - bfval(h));
  } else if (idx < 24576) {
    int i2 = idx - 16384;
    int c = i2 >> 7, k = i2 & 127;
    float w = W2[k * 64 + c];
    unsigned short h = f2bf(w);
    wt2h[i2] = h;
    wt2l[i2] = f2bf(w - bfval(h));
  }
}

// ---------------- Bucketed CSR (dest-keyed) build ----------------

__global__ __launch_bounds__(256) void bucket_count_kernel(const int* __restrict__ col,
                                                           int* __restrict__ bcnt) {
  __shared__ int h[NBK];
  const int tid = threadIdx.x;
  for (int i = tid; i < NBK; i += 256) h[i] = 0;
  __syncthreads();
  const int base = blockIdx.x * CHUNK;
  for (int i = tid; i < CHUNK; i += 256) atomicAdd(&h[col[base + i] >> 8], 1);
  __syncthreads();
  for (int i = tid; i < NBK; i += 256)
    if (h[i]) atomicAdd(&bcnt[i], h[i]);
}

// scatter with in-kernel scan of bcnt (replaces scan196_kernel)
__global__ __launch_bounds__(256) void bucket_scatter_kernel(
    const int* __restrict__ row, const int* __restrict__ col,
    const int* __restrict__ bcnt, int* __restrict__ bfill,
    unsigned int* __restrict__ ebuf) {
  __shared__ int h[NBK], gst[NBK], h2[NBK], boffl[NBK], sc[256];
  const int tid = threadIdx.x;
  for (int i = tid; i < NBK; i += 256) { h[i] = 0; h2[i] = 0; }
  // in-LDS exclusive scan of bcnt[0..195]
  int v = (tid < NBK) ? bcnt[tid] : 0;
  sc[tid] = v;
  __syncthreads();
  for (int off = 1; off < 256; off <<= 1) {
    int u = (tid >= off) ? sc[tid - off] : 0;
    __syncthreads();
    sc[tid] += u;
    __syncthreads();
  }
  if (tid < NBK) boffl[tid] = sc[tid] - v;
  __syncthreads();

  const int base = blockIdx.x * CHUNK;
  for (int i = tid; i < CHUNK; i += 256) atomicAdd(&h[col[base + i] >> 8], 1);
  __syncthreads();
  for (int i = tid; i < NBK; i += 256) gst[i] = h[i] ? atomicAdd(&bfill[i], h[i]) : 0;
  __syncthreads();
  for (int i = tid; i < CHUNK; i += 256) {
    int c = col[base + i];
    int b = c >> 8;
    int r = atomicAdd(&h2[b], 1);
    unsigned int packed = ((unsigned int)row[base + i] << 8) | (unsigned int)(c & 255);
    ebuf[boffl[b] + gst[b] + r] = packed;  // contiguous run per (block,bucket)
  }
}

// build with in-kernel scan (one block per bucket)
__global__ __launch_bounds__(256) void bucket_build_kernel(
    const unsigned int* __restrict__ ebuf, const int* __restrict__ bcnt,
    int* __restrict__ row_ptr, float* __restrict__ dis, int* __restrict__ csr, int n) {
  __shared__ int cnt[256], c2[256], lbase[256], wsum[4], sc[256], cb[256];
  const int tid = threadIdx.x;
  const int b = blockIdx.x;

  // scan bcnt to find this bucket's span [s0, s1)
  int v = (tid < NBK) ? bcnt[tid] : 0;
  sc[tid] = v;
  cb[tid] = v;
  cnt[tid] = 0;
  c2[tid] = 0;
  __syncthreads();
  for (int off = 1; off < 256; off <<= 1) {
    int u = (tid >= off) ? sc[tid - off] : 0;
    __syncthreads();
    sc[tid] += u;
    __syncthreads();
  }
  const int s1 = sc[b];
  const int s0 = s1 - cb[b];

  for (int i = s0 + tid; i < s1; i += 256) atomicAdd(&cnt[ebuf[i] & 255], 1);
  __syncthreads();

  const int lane = tid & 63, w = tid >> 6;
  int c = cnt[tid];
  int inc = c;
#pragma unroll
  for (int off = 1; off < 64; off <<= 1) {
    int u = __shfl_up(inc, off);
    if (lane >= off) inc += u;
  }
  if (lane == 63) wsum[w] = inc;
  __syncthreads();
  int wo = 0;
  for (int i = 0; i < w; ++i) wo += wsum[i];
  const int excl = wo + inc - c;

  const int node = b * 256 + tid;
  if (node <= n) row_ptr[node] = s0 + excl;
  if (node < n) dis[node] = rsqrtf((float)(c + 1));
  lbase[tid] = s0 + excl;
  __syncthreads();

  for (int i = s0 + tid; i < s1; i += 256) {
    unsigned int p = ebuf[i];
    int dl = p & 255;
    int r = atomicAdd(&c2[dl], 1);
    csr[lbase[dl] + r] = (int)(p >> 8);
  }
}

// ---------------- MFMA GEMM: 2-phase dbuf global_load_lds (R15-proven) ----------------

template <int BM, int NCOLS, bool AF32, bool OUTBF16>
__global__ __launch_bounds__(256) void gemm_mfma_kernel(
    const void* __restrict__ Av, const unsigned short* __restrict__ Bth,
    const unsigned short* __restrict__ Btl, const float* __restrict__ dis,
    void* __restrict__ outv, int M) {
  constexpr int WCOL = NCOLS / 64;
  constexpr int WROW = 4 / WCOL;
  constexpr int RG = BM / (WROW * 16);
  constexpr int A_BYTES = BM * 32 * (AF32 ? 4 : 2);
  constexpr int B_BYTES = NCOLS * 32 * 2;
  constexpr int TILE_BYTES = A_BYTES + 2 * B_BYTES;
  constexpr int STAGE_BYTES = 2 * TILE_BYTES;
  constexpr int EPI_PITCH = OUTBF16 ? (NCOLS + 8) : (NCOLS + 4);
  constexpr int EPI_BYTES = BM * EPI_PITCH * (OUTBF16 ? 2 : 4);
  constexpr int SMEM_BYTES = STAGE_BYTES > EPI_BYTES ? STAGE_BYTES : EPI_BYTES;

  __shared__ __align__(16) unsigned char smem[SMEM_BYTES];

  const int t = threadIdx.x;
  const int lane = t & 63;
  const int l15 = lane & 15;
  const int lg = lane >> 4;
  const int wv = t >> 6;
  const int wr = wv % WROW;
  const int wc = wv / WROW;
  const int rb = blockIdx.x * BM;

  auto stage = [&](int kt, int buf) {
    unsigned char* base = smem + buf * TILE_BYTES;
    if constexpr (AF32) {
      constexpr int CPW = (BM * 128 / 1024) / 4;
#pragma unroll
      for (int j = 0; j < CPW; ++j) {
        int callr = (wv * CPW + j) * 8;
        int gr = min(rb + callr + (lane >> 3), M - 1);
        const float* gp = (const float*)Av + (size_t)gr * 128 + kt * 32 + (lane & 7) * 4;
        gload_lds16(gp, base + callr * 128);
      }
    } else {
      constexpr int CPW = (BM * 64 / 1024) / 4;
#pragma unroll
      for (int j = 0; j < CPW; ++j) {
        int callr = (wv * CPW + j) * 16;
        int gr = min(rb + callr + (lane >> 2), M - 1);
        const unsigned short* gp =
            (const unsigned short*)Av + (size_t)gr * 128 + kt * 32 + (lane & 3) * 8;
        gload_lds16(gp, base + callr * 64);
      }
    }
    {
      constexpr int CPW = (NCOLS * 64 / 1024) / 4;
#pragma unroll
      for (int j = 0; j < CPW; ++j) {
        int callr = (wv * CPW + j) * 16;
        int r = callr + (lane >> 2);
        size_t goff = (size_t)r * 128 + kt * 32 + (lane & 3) * 8;
        gload_lds16(Bth + goff, base + A_BYTES + callr * 64);
        gload_lds16(Btl + goff, base + A_BYTES + B_BYTES + callr * 64);
      }
    }
  };

  f4v acc[RG][4];
#pragma unroll
  for (int i = 0; i < RG; ++i)
#pragma unroll
    for (int j = 0; j < 4; ++j) acc[i][j] = (f4v){0.f, 0.f, 0.f, 0.f};

  stage(0, 0);
  __syncthreads();  // vmcnt(0) drain -> tile 0 landed

#pragma unroll
  for (int kt = 0; kt < 4; ++kt) {
    const int buf = kt & 1;
    if (kt < 3) stage(kt + 1, buf ^ 1);  // async prefetch; overlaps compute below

    const unsigned char* tb = smem + buf * TILE_BYTES;
    s8v afh[RG], afl[RG];
#pragma unroll
    for (int rg = 0; rg < RG; ++rg) {
      int row = wr * (RG * 16) + rg * 16 + l15;
      if constexpr (AF32) {
        const float* ap = (const float*)tb + row * 32 + lg * 8;
        float4 x0 = *reinterpret_cast<const float4*>(ap);
        float4 x1 = *reinterpret_cast<const float4*>(ap + 4);
        float f[8] = {x0.x, x0.y, x0.z, x0.w, x1.x, x1.y, x1.z, x1.w};
#pragma unroll
        for (int q = 0; q < 8; ++q) {
          unsigned short hq = f2bf(f[q]);
          afh[rg][q] = (short)hq;
          afl[rg][q] = (short)f2bf(f[q] - bfval(hq));
        }
      } else {
        afh[rg] = *reinterpret_cast<const s8v*>((const unsigned short*)tb + row * 32 + lg * 8);
      }
    }
#pragma unroll
    for (int cg = 0; cg < 4; ++cg) {
      int colr = wc * 64 + cg * 16 + l15;
      s8v bh = *reinterpret_cast<const s8v*>(
          (const unsigned short*)(tb + A_BYTES) + colr * 32 + lg * 8);
      s8v bl = *reinterpret_cast<const s8v*>(
          (const unsigned short*)(tb + A_BYTES + B_BYTES) + colr * 32 + lg * 8);
#pragma unroll
      for (int rg = 0; rg < RG; ++rg) {
        acc[rg][cg] = __builtin_amdgcn_mfma_f32_16x16x32_bf16(afh[rg], bh, acc[rg][cg], 0, 0, 0);
        acc[rg][cg] = __builtin_amdgcn_mfma_f32_16x16x32_bf16(afh[rg], bl, acc[rg][cg], 0, 0, 0);
        if constexpr (AF32)
          acc[rg][cg] = __builtin_amdgcn_mfma_f32_16x16x32_bf16(afl[rg], bh, acc[rg][cg], 0, 0, 0);
      }
    }
    __syncthreads();  // drains vmcnt(0) (tile kt+1 landed) + all waves done reading buf
  }

  // ---- epilogue: scale, stage to LDS, coalesced store ----
  float dv[RG][4];
#pragma unroll
  for (int rg = 0; rg < RG; ++rg)
#pragma unroll
    for (int g = 0; g < 4; ++g) {
      int r = rb + wr * (RG * 16) + rg * 16 + lg * 4 + g;
      dv[rg][g] = (r < M) ? dis[r] : 0.f;
    }

#pragma unroll
  for (int rg = 0; rg < RG; ++rg)
#pragma unroll
    for (int cg = 0; cg < 4; ++cg) {
      int colc = wc * 64 + cg * 16 + l15;
#pragma unroll
      for (int g = 0; g < 4; ++g) {
        int r = wr * (RG * 16) + rg * 16 + lg * 4 + g;  // block-local row
        float o = acc[rg][cg][g] * dv[rg][g];
        if constexpr (OUTBF16)
          ((unsigned short*)smem)[r * EPI_PITCH + colc] = f2bf(o);
        else
          ((float*)smem)[r * EPI_PITCH + colc] = o;
      }
    }
  __syncthreads();

  constexpr int CHR = OUTBF16 ? (NCOLS / 8) : (NCOLS / 4);
#pragma unroll
  for (int itc = 0; itc < BM * CHR / 256; ++itc) {
    int ch = t + itc * 256;
    int r = ch / CHR, cc = ch % CHR;
    if (rb + r < M) {
      if constexpr (OUTBF16) {
        int4 v = *reinterpret_cast<const int4*>(&((unsigned short*)smem)[r * EPI_PITCH + cc * 8]);
        *reinterpret_cast<int4*>(&((unsigned short*)outv)[(size_t)(rb + r) * NCOLS + cc * 8]) = v;
      } else {
        int4 v = *reinterpret_cast<const int4*>(&((float*)smem)[r * EPI_PITCH + cc * 4]);
        *reinterpret_cast<int4*>(&((float*)outv)[(size_t)(rb + r) * NCOLS + cc * 4]) = v;
      }
    }
  }
}

// ---------------- Aggregation (unroll 8; 32-bit gather offsets) ----------------

__global__ __launch_bounds__(256) void agg_bf16_kernel(
    const unsigned int* __restrict__ H, const int* __restrict__ row_ptr,
    const int* __restrict__ csr, const float* __restrict__ dis,
    const float* __restrict__ bias, unsigned int* __restrict__ Z, int n) {
  const int lane = threadIdx.x & 63;
  const int node = blockIdx.x * 4 + (threadIdx.x >> 6);
  if (node >= n) return;

  float2 a[8];
  a[0] = bfpair(H[node * 64 + lane]);  // self-loop (32-bit indexing)
#pragma unroll
  for (int i = 1; i < 8; ++i) a[i] = make_float2(0.f, 0.f);

  const int s0 = row_ptr[node], s1 = row_ptr[node + 1];
  for (int e = s0; e < s1; e += 64) {
    int m = s1 - e;
    if (m > 64) m = 64;
    int idx = 0;
    if (lane < m) idx = csr[e + lane];
    int j = 0;
    for (; j + 8 <= m; j += 8) {
      int o0 = __shfl(idx, j) * 64 + lane,     o1 = __shfl(idx, j + 1) * 64 + lane;
      int o2 = __shfl(idx, j + 2) * 64 + lane, o3 = __shfl(idx, j + 3) * 64 + lane;
      int o4 = __shfl(idx, j + 4) * 64 + lane, o5 = __shfl(idx, j + 5) * 64 + lane;
      int o6 = __shfl(idx, j + 6) * 64 + lane, o7 = __shfl(idx, j + 7) * 64 + lane;
      float2 v0 = bfpair(H[o0]);
      float2 v1 = bfpair(H[o1]);
      float2 v2 = bfpair(H[o2]);
      float2 v3 = bfpair(H[o3]);
      float2 v4 = bfpair(H[o4]);
      float2 v5 = bfpair(H[o5]);
      float2 v6 = bfpair(H[o6]);
      float2 v7 = bfpair(H[o7]);
      a[0].x += v0.x; a[0].y += v0.y;  a[1].x += v1.x; a[1].y += v1.y;
      a[2].x += v2.x; a[2].y += v2.y;  a[3].x += v3.x; a[3].y += v3.y;
      a[4].x += v4.x; a[4].y += v4.y;  a[5].x += v5.x; a[5].y += v5.y;
      a[6].x += v6.x; a[6].y += v6.y;  a[7].x += v7.x; a[7].y += v7.y;
    }
    for (; j + 4 <= m; j += 4) {
      int o0 = __shfl(idx, j) * 64 + lane,     o1 = __shfl(idx, j + 1) * 64 + lane;
      int o2 = __shfl(idx, j + 2) * 64 + lane, o3 = __shfl(idx, j + 3) * 64 + lane;
      float2 v0 = bfpair(H[o0]);
      float2 v1 = bfpair(H[o1]);
      float2 v2 = bfpair(H[o2]);
      float2 v3 = bfpair(H[o3]);
      a[0].x += v0.x; a[0].y += v0.y;  a[1].x += v1.x; a[1].y += v1.y;
      a[2].x += v2.x; a[2].y += v2.y;  a[3].x += v3.x; a[3].y += v3.y;
    }
    for (; j < m; ++j) {
      float2 v = bfpair(H[__shfl(idx, j) * 64 + lane]);
      a[0].x += v.x; a[0].y += v.y;
    }
  }
  const float d = dis[node];
  float2 b = *reinterpret_cast<const float2*>(&bias[lane * 2]);
  float sx = ((a[0].x + a[1].x) + (a[2].x + a[3].x)) + ((a[4].x + a[5].x) + (a[6].x + a[7].x));
  float sy = ((a[0].y + a[1].y) + (a[2].y + a[3].y)) + ((a[4].y + a[5].y) + (a[6].y + a[7].y));
  float ox = fmaxf(sx * d + b.x, 0.f);
  float oy = fmaxf(sy * d + b.y, 0.f);
  Z[node * 64 + lane] = (unsigned int)f2bf(ox) | ((unsigned int)f2bf(oy) << 16);
}

__global__ __launch_bounds__(256) void agg_f32_kernel(
    const float* __restrict__ Hs, const int* __restrict__ row_ptr,
    const int* __restrict__ csr, const float* __restrict__ dis,
    const float* __restrict__ bias, float* __restrict__ out, int n) {
  const int lane = threadIdx.x & 63;
  const int node = blockIdx.x * 4 + (threadIdx.x >> 6);
  if (node >= n) return;

  float a[8];
  a[0] = Hs[node * 64 + lane];  // self-loop (32-bit indexing)
#pragma unroll
  for (int i = 1; i < 8; ++i) a[i] = 0.f;

  const int s0 = row_ptr[node], s1 = row_ptr[node + 1];
  for (int e = s0; e < s1; e += 64) {
    int m = s1 - e;
    if (m > 64) m = 64;
    int idx = 0;
    if (lane < m) idx = csr[e + lane];
    int j = 0;
    for (; j + 8 <= m; j += 8) {
      int o0 = __shfl(idx, j) * 64 + lane,     o1 = __shfl(idx, j + 1) * 64 + lane;
      int o2 = __shfl(idx, j + 2) * 64 + lane, o3 = __shfl(idx, j + 3) * 64 + lane;
      int o4 = __shfl(idx, j + 4) * 64 + lane, o5 = __shfl(idx, j + 5) * 64 + lane;
      int o6 = __shfl(idx, j + 6) * 64 + lane, o7 = __shfl(idx, j + 7) * 64 + lane;
      float v0 = Hs[o0];
      float v1 = Hs[o1];
      float v2 = Hs[o2];
      float v3 = Hs[o3];
      float v4 = Hs[o4];
      float v5 = Hs[o5];
      float v6 = Hs[o6];
      float v7 = Hs[o7];
      a[0] += v0; a[1] += v1; a[2] += v2; a[3] += v3;
      a[4] += v4; a[5] += v5; a[6] += v6; a[7] += v7;
    }
    for (; j + 4 <= m; j += 4) {
      int o0 = __shfl(idx, j) * 64 + lane,     o1 = __shfl(idx, j + 1) * 64 + lane;
      int o2 = __shfl(idx, j + 2) * 64 + lane, o3 = __shfl(idx, j + 3) * 64 + lane;
      float v0 = Hs[o0];
      float v1 = Hs[o1];
      float v2 = Hs[o2];
      float v3 = Hs[o3];
      a[0] += v0; a[1] += v1; a[2] += v2; a[3] += v3;
    }
    for (; j < m; ++j) a[0] += Hs[__shfl(idx, j) * 64 + lane];
  }
  float s = ((a[0] + a[1]) + (a[2] + a[3])) + ((a[4] + a[5]) + (a[6] + a[7]));
  out[node * 64 + lane] = s * dis[node] + bias[lane];
}

// ---------------- launch ----------------

extern "C" void kernel_launch(void* const* d_in, const int* in_sizes, int n_in,
                              void* d_out, int out_size, void* d_ws, size_t ws_size,
                              hipStream_t stream) {
  const float* x  = (const float*)d_in[0];
  const int*   ei = (const int*)d_in[1];
  const float* W1 = (const float*)d_in[2];
  const float* b1 = (const float*)d_in[3];
  const float* W2 = (const float*)d_in[4];
  const float* b2 = (const float*)d_in[5];
  float* out = (float*)d_out;

  const int* row = ei;        // source nodes
  const int* col = ei + NE;   // destination nodes

  char* ws = (char*)d_ws;
  size_t off = 0;
  auto alloc = [&](size_t bytes) -> void* {
    off = (off + 255) & ~(size_t)255;
    void* p = ws + off;
    off += bytes;
    return p;
  };

  int* bcnt    = (int*)alloc((size_t)2 * NBK * sizeof(int));  // bcnt | bfill
  int* bfill   = bcnt + NBK;
  unsigned int* ebuf = (unsigned int*)alloc((size_t)NE * sizeof(unsigned int));
  int* row_ptr = (int*)alloc((size_t)(NN + 1) * sizeof(int));
  int* csr     = (int*)alloc((size_t)NE * sizeof(int));
  float* dis   = (float*)alloc((size_t)NN * sizeof(float));
  unsigned short* wt1h = (unsigned short*)alloc((size_t)(2 * 128 * 128 + 2 * 64 * 128) * 2);
  unsigned short* wt1l = wt1h + 128 * 128;
  unsigned short* wt2h = wt1l + 128 * 128;
  unsigned short* wt2l = wt2h + 64 * 128;
  // HT region: bf16 [NN][128] for layer-1 GEMM out, then f32 [NN][64] for layer-2
  unsigned short* HT16 = (unsigned short*)alloc((size_t)NN * 128 * 2);
  float* HT32 = (float*)HT16;
  unsigned int* HTu = (unsigned int*)HT16;
  unsigned short* Z1 = (unsigned short*)alloc((size_t)NN * 128 * 2);
  unsigned int* Z1u = (unsigned int*)Z1;

  wprep_kernel<<<97, 256, 0, stream>>>(W1, W2, wt1h, wt1l, wt2h, wt2l, bcnt);
  bucket_count_kernel<<<NE / CHUNK, 256, 0, stream>>>(col, bcnt);
  bucket_scatter_kernel<<<NE / CHUNK, 256, 0, stream>>>(row, col, bcnt, bfill, ebuf);
  bucket_build_kernel<<<NBK, 256, 0, stream>>>(ebuf, bcnt, row_ptr, dis, csr, NN);

  const int ga = (NN + 3) / 4;

  // Layer 1: HT16 = bf16( dis .* (X @ W1) )  [NN][128], BM=64 -> 782 blocks
  gemm_mfma_kernel<64, 128, true, true><<<(NN + 63) / 64, 256, 0, stream>>>(
      x, wt1h, wt1l, dis, HT16, NN);
  agg_bf16_kernel<<<ga, 256, 0, stream>>>(HTu, row_ptr, csr, dis, b1, Z1u, NN);

  // Layer 2: HT32 = dis .* (Z1 @ W2)  [NN][64], BM=128 -> 391 blocks
  gemm_mfma_kernel<128, 64, false, false><<<(NN + 127) / 128, 256, 0, stream>>>(
      Z1, wt2h, wt2l, dis, HT32, NN);
  agg_f32_kernel<<<ga, 256, 0, stream>>>(HT32, row_ptr, csr, dis, b2, out, NN);
}

// Round 17
// 120.037 us; speedup vs baseline: 1.8987x; 1.0334x over previous
//
#include <hip/hip_runtime.h>

#define NN 50000
#define NE 640000
#define NBK 196      // buckets of 256 nodes
#define CHUNK 2560   // edges per block in bucket passes: NE/CHUNK = 250

typedef __attribute__((ext_vector_type(8))) short s8v;
typedef __attribute__((ext_vector_type(4))) float f4v;

__device__ __forceinline__ unsigned short f2bf(float x) {  // RNE f32->bf16
  unsigned int u = __float_as_uint(x);
  return (unsigned short)((u + 0x7fffu + ((u >> 16) & 1u)) >> 16);
}
__device__ __forceinline__ float bfval(unsigned short h) {
  return __uint_as_float((unsigned int)h << 16);
}
__device__ __forceinline__ float2 bfpair(unsigned int u) {
  float2 r;
  r.x = __uint_as_float((u & 0xffffu) << 16);
  r.y = __uint_as_float(u & 0xffff0000u);
  return r;
}

// async global->LDS, 16B per lane; LDS dest = wave-uniform base + lane*16
__device__ __forceinline__ void gload_lds16(const void* g, void* l) {
  __builtin_amdgcn_global_load_lds(
      (const __attribute__((address_space(1))) void*)g,
      (__attribute__((address_space(3))) void*)l, 16, 0, 0);
}

// ---------------- W prep + bcnt|bfill zero + zero-rows for agg masking ----------------

__global__ __launch_bounds__(256) void wprep_kernel(
    const float* __restrict__ W1, const float* __restrict__ W2,
    unsigned short* __restrict__ wt1h, unsigned short* __restrict__ wt1l,
    unsigned short* __restrict__ wt2h, unsigned short* __restrict__ wt2l,
    int* __restrict__ bcnt, unsigned int* __restrict__ htz, unsigned int* __restrict__ z1z) {
  const int b = blockIdx.x;
  const int t = threadIdx.x;
  if (b == 96) {
    for (int i = t; i < 2 * NBK; i += 256) bcnt[i] = 0;  // bcnt | bfill
    if (t < 64) htz[t] = 0u;  // HT row NN (256B) -- agg gather zero-row
    if (t < 64) z1z[t] = 0u;  // Z1 row NN (256B)
    return;
  }
  int idx = b * 256 + t;  // 0..24575
  if (idx < 16384) {
    int c = idx >> 7, k = idx & 127;
    float w = W1[k * 128 + c];
    unsigned short h = f2bf(w);
    wt1h[idx] = h;
    wt1l[idx] = f2bf(w - bfval(h));
  } else if (idx < 24576) {
    int i2 = idx - 16384;
    int c = i2 >> 7, k = i2 & 127;
    float w = W2[k * 64 + c];
    unsigned short h = f2bf(w);
    wt2h[i2] = h;
    wt2l[i2] = f2bf(w - bfval(h));
  }
}

// ---------------- Bucketed CSR (dest-keyed) build ----------------

__global__ __launch_bounds__(256) void bucket_count_kernel(const int* __restrict__ col,
                                                           int* __restrict__ bcnt) {
  __shared__ int h[NBK];
  const int tid = threadIdx.x;
  for (int i = tid; i < NBK; i += 256) h[i] = 0;
  __syncthreads();
  const int base = blockIdx.x * CHUNK;
  for (int i = tid; i < CHUNK; i += 256) atomicAdd(&h[col[base + i] >> 8], 1);
  __syncthreads();
  for (int i = tid; i < NBK; i += 256)
    if (h[i]) atomicAdd(&bcnt[i], h[i]);
}

__global__ __launch_bounds__(256) void bucket_scatter_kernel(
    const int* __restrict__ row, const int* __restrict__ col,
    const int* __restrict__ bcnt, int* __restrict__ bfill,
    unsigned int* __restrict__ ebuf) {
  __shared__ int h[NBK], gst[NBK], h2[NBK], boffl[NBK], sc[256];
  const int tid = threadIdx.x;
  for (int i = tid; i < NBK; i += 256) { h[i] = 0; h2[i] = 0; }
  int v = (tid < NBK) ? bcnt[tid] : 0;
  sc[tid] = v;
  __syncthreads();
  for (int off = 1; off < 256; off <<= 1) {
    int u = (tid >= off) ? sc[tid - off] : 0;
    __syncthreads();
    sc[tid] += u;
    __syncthreads();
  }
  if (tid < NBK) boffl[tid] = sc[tid] - v;
  __syncthreads();

  const int base = blockIdx.x * CHUNK;
  for (int i = tid; i < CHUNK; i += 256) atomicAdd(&h[col[base + i] >> 8], 1);
  __syncthreads();
  for (int i = tid; i < NBK; i += 256) gst[i] = h[i] ? atomicAdd(&bfill[i], h[i]) : 0;
  __syncthreads();
  for (int i = tid; i < CHUNK; i += 256) {
    int c = col[base + i];
    int b = c >> 8;
    int r = atomicAdd(&h2[b], 1);
    unsigned int packed = ((unsigned int)row[base + i] << 8) | (unsigned int)(c & 255);
    ebuf[boffl[b] + gst[b] + r] = packed;
  }
}

__global__ __launch_bounds__(256) void bucket_build_kernel(
    const unsigned int* __restrict__ ebuf, const int* __restrict__ bcnt,
    int* __restrict__ row_ptr, float* __restrict__ dis, int* __restrict__ csr, int n) {
  __shared__ int cnt[256], c2[256], lbase[256], wsum[4], sc[256], cb[256];
  const int tid = threadIdx.x;
  const int b = blockIdx.x;

  int v = (tid < NBK) ? bcnt[tid] : 0;
  sc[tid] = v;
  cb[tid] = v;
  cnt[tid] = 0;
  c2[tid] = 0;
  __syncthreads();
  for (int off = 1; off < 256; off <<= 1) {
    int u = (tid >= off) ? sc[tid - off] : 0;
    __syncthreads();
    sc[tid] += u;
    __syncthreads();
  }
  const int s1 = sc[b];
  const int s0 = s1 - cb[b];

  for (int i = s0 + tid; i < s1; i += 256) atomicAdd(&cnt[ebuf[i] & 255], 1);
  __syncthreads();

  const int lane = tid & 63, w = tid >> 6;
  int c = cnt[tid];
  int inc = c;
#pragma unroll
  for (int off = 1; off < 64; off <<= 1) {
    int u = __shfl_up(inc, off);
    if (lane >= off) inc += u;
  }
  if (lane == 63) wsum[w] = inc;
  __syncthreads();
  int wo = 0;
  for (int i = 0; i < w; ++i) wo += wsum[i];
  const int excl = wo + inc - c;

  const int node = b * 256 + tid;
  if (node <= n) row_ptr[node] = s0 + excl;
  if (node < n) dis[node] = rsqrtf((float)(c + 1));
  lbase[tid] = s0 + excl;
  __syncthreads();

  for (int i = s0 + tid; i < s1; i += 256) {
    unsigned int p = ebuf[i];
    int dl = p & 255;
    int r = atomicAdd(&c2[dl], 1);
    csr[lbase[dl] + r] = (int)(p >> 8);
  }
}

// ---------------- MFMA GEMM: 2-phase dbuf global_load_lds (R15/R16-proven) ----------------

template <int BM, int NCOLS, bool AF32, bool OUTBF16>
__global__ __launch_bounds__(256) void gemm_mfma_kernel(
    const void* __restrict__ Av, const unsigned short* __restrict__ Bth,
    const unsigned short* __restrict__ Btl, const float* __restrict__ dis,
    void* __restrict__ outv, int M) {
  constexpr int WCOL = NCOLS / 64;
  constexpr int WROW = 4 / WCOL;
  constexpr int RG = BM / (WROW * 16);
  constexpr int A_BYTES = BM * 32 * (AF32 ? 4 : 2);
  constexpr int B_BYTES = NCOLS * 32 * 2;
  constexpr int TILE_BYTES = A_BYTES + 2 * B_BYTES;
  constexpr int STAGE_BYTES = 2 * TILE_BYTES;
  constexpr int EPI_PITCH = OUTBF16 ? (NCOLS + 8) : (NCOLS + 4);
  constexpr int EPI_BYTES = BM * EPI_PITCH * (OUTBF16 ? 2 : 4);
  constexpr int SMEM_BYTES = STAGE_BYTES > EPI_BYTES ? STAGE_BYTES : EPI_BYTES;

  __shared__ __align__(16) unsigned char smem[SMEM_BYTES];

  const int t = threadIdx.x;
  const int lane = t & 63;
  const int l15 = lane & 15;
  const int lg = lane >> 4;
  const int wv = t >> 6;
  const int wr = wv % WROW;
  const int wc = wv / WROW;
  const int rb = blockIdx.x * BM;

  auto stage = [&](int kt, int buf) {
    unsigned char* base = smem + buf * TILE_BYTES;
    if constexpr (AF32) {
      constexpr int CPW = (BM * 128 / 1024) / 4;
#pragma unroll
      for (int j = 0; j < CPW; ++j) {
        int callr = (wv * CPW + j) * 8;
        int gr = min(rb + callr + (lane >> 3), M - 1);
        const float* gp = (const float*)Av + (size_t)gr * 128 + kt * 32 + (lane & 7) * 4;
        gload_lds16(gp, base + callr * 128);
      }
    } else {
      constexpr int CPW = (BM * 64 / 1024) / 4;
#pragma unroll
      for (int j = 0; j < CPW; ++j) {
        int callr = (wv * CPW + j) * 16;
        int gr = min(rb + callr + (lane >> 2), M - 1);
        const unsigned short* gp =
            (const unsigned short*)Av + (size_t)gr * 128 + kt * 32 + (lane & 3) * 8;
        gload_lds16(gp, base + callr * 64);
      }
    }
    {
      constexpr int CPW = (NCOLS * 64 / 1024) / 4;
#pragma unroll
      for (int j = 0; j < CPW; ++j) {
        int callr = (wv * CPW + j) * 16;
        int r = callr + (lane >> 2);
        size_t goff = (size_t)r * 128 + kt * 32 + (lane & 3) * 8;
        gload_lds16(Bth + goff, base + A_BYTES + callr * 64);
        gload_lds16(Btl + goff, base + A_BYTES + B_BYTES + callr * 64);
      }
    }
  };

  f4v acc[RG][4];
#pragma unroll
  for (int i = 0; i < RG; ++i)
#pragma unroll
    for (int j = 0; j < 4; ++j) acc[i][j] = (f4v){0.f, 0.f, 0.f, 0.f};

  stage(0, 0);
  __syncthreads();

#pragma unroll
  for (int kt = 0; kt < 4; ++kt) {
    const int buf = kt & 1;
    if (kt < 3) stage(kt + 1, buf ^ 1);

    const unsigned char* tb = smem + buf * TILE_BYTES;
    s8v afh[RG], afl[RG];
#pragma unroll
    for (int rg = 0; rg < RG; ++rg) {
      int row = wr * (RG * 16) + rg * 16 + l15;
      if constexpr (AF32) {
        const float* ap = (const float*)tb + row * 32 + lg * 8;
        float4 x0 = *reinterpret_cast<const float4*>(ap);
        float4 x1 = *reinterpret_cast<const float4*>(ap + 4);
        float f[8] = {x0.x, x0.y, x0.z, x0.w, x1.x, x1.y, x1.z, x1.w};
#pragma unroll
        for (int q = 0; q < 8; ++q) {
          unsigned short hq = f2bf(f[q]);
          afh[rg][q] = (short)hq;
          afl[rg][q] = (short)f2bf(f[q] - bfval(hq));
        }
      } else {
        afh[rg] = *reinterpret_cast<const s8v*>((const unsigned short*)tb + row * 32 + lg * 8);
      }
    }
#pragma unroll
    for (int cg = 0; cg < 4; ++cg) {
      int colr = wc * 64 + cg * 16 + l15;
      s8v bh = *reinterpret_cast<const s8v*>(
          (const unsigned short*)(tb + A_BYTES) + colr * 32 + lg * 8);
      s8v bl = *reinterpret_cast<const s8v*>(
          (const unsigned short*)(tb + A_BYTES + B_BYTES) + colr * 32 + lg * 8);
#pragma unroll
      for (int rg = 0; rg < RG; ++rg) {
        acc[rg][cg] = __builtin_amdgcn_mfma_f32_16x16x32_bf16(afh[rg], bh, acc[rg][cg], 0, 0, 0);
        acc[rg][cg] = __builtin_amdgcn_mfma_f32_16x16x32_bf16(afh[rg], bl, acc[rg][cg], 0, 0, 0);
        if constexpr (AF32)
          acc[rg][cg] = __builtin_amdgcn_mfma_f32_16x16x32_bf16(afl[rg], bh, acc[rg][cg], 0, 0, 0);
      }
    }
    __syncthreads();
  }

  float dv[RG][4];
#pragma unroll
  for (int rg = 0; rg < RG; ++rg)
#pragma unroll
    for (int g = 0; g < 4; ++g) {
      int r = rb + wr * (RG * 16) + rg * 16 + lg * 4 + g;
      dv[rg][g] = (r < M) ? dis[r] : 0.f;
    }

#pragma unroll
  for (int rg = 0; rg < RG; ++rg)
#pragma unroll
    for (int cg = 0; cg < 4; ++cg) {
      int colc = wc * 64 + cg * 16 + l15;
#pragma unroll
      for (int g = 0; g < 4; ++g) {
        int r = wr * (RG * 16) + rg * 16 + lg * 4 + g;
        float o = acc[rg][cg][g] * dv[rg][g];
        if constexpr (OUTBF16)
          ((unsigned short*)smem)[r * EPI_PITCH + colc] = f2bf(o);
        else
          ((float*)smem)[r * EPI_PITCH + colc] = o;
      }
    }
  __syncthreads();

  constexpr int CHR = OUTBF16 ? (NCOLS / 8) : (NCOLS / 4);
#pragma unroll
  for (int itc = 0; itc < BM * CHR / 256; ++itc) {
    int ch = t + itc * 256;
    int r = ch / CHR, cc = ch % CHR;
    if (rb + r < M) {
      if constexpr (OUTBF16) {
        int4 v = *reinterpret_cast<const int4*>(&((unsigned short*)smem)[r * EPI_PITCH + cc * 8]);
        *reinterpret_cast<int4*>(&((unsigned short*)outv)[(size_t)(rb + r) * NCOLS + cc * 8]) = v;
      } else {
        int4 v = *reinterpret_cast<const int4*>(&((float*)smem)[r * EPI_PITCH + cc * 4]);
        *reinterpret_cast<int4*>(&((float*)outv)[(size_t)(rb + r) * NCOLS + cc * 4]) = v;
      }
    }
  }
}

// ---------------- Aggregation: 2 nodes per wave (lanes 0-31 / 32-63), zero-row masking ----

// H2: uint2 rows of 32 (128 bf16 ch); node row NN is all-zero (gather target for masked j).
__global__ __launch_bounds__(256) void agg_bf16_kernel(
    const uint2* __restrict__ H2, const int* __restrict__ row_ptr,
    const int* __restrict__ csr, const float* __restrict__ dis,
    const float* __restrict__ bias, uint2* __restrict__ Z2, int n) {
  const int lane = threadIdx.x & 63;
  const int sub = lane & 31;
  int node = blockIdx.x * 8 + ((threadIdx.x >> 6) << 1) + (lane >> 5);
  if (node >= n) node = n - 1;  // n%8==0 -> unreachable; safety

  const int s0 = row_ptr[node], s1 = row_ptr[node + 1];
  const int m = s1 - s0;
  const int mo = __shfl(m, lane ^ 32);
  const int mmax = m > mo ? m : mo;

  float4 a[8];
  {
    uint2 v = H2[node * 32 + sub];
    float2 p0 = bfpair(v.x), p1 = bfpair(v.y);
    a[0] = make_float4(p0.x, p0.y, p1.x, p1.y);
  }
#pragma unroll
  for (int i = 1; i < 8; ++i) a[i] = make_float4(0.f, 0.f, 0.f, 0.f);

  for (int e = 0; e < mmax; e += 32) {
    int idx = n;  // zero-row
    if (sub < m - e) idx = csr[s0 + e + sub];
    int jm = mmax - e;
    if (jm > 32) jm = 32;
    int j = 0;
    for (; j + 8 <= jm; j += 8) {
      int r0 = __shfl(idx, j, 32),     r1 = __shfl(idx, j + 1, 32);
      int r2 = __shfl(idx, j + 2, 32), r3 = __shfl(idx, j + 3, 32);
      int r4 = __shfl(idx, j + 4, 32), r5 = __shfl(idx, j + 5, 32);
      int r6 = __shfl(idx, j + 6, 32), r7 = __shfl(idx, j + 7, 32);
      uint2 v0 = H2[r0 * 32 + sub], v1 = H2[r1 * 32 + sub];
      uint2 v2 = H2[r2 * 32 + sub], v3 = H2[r3 * 32 + sub];
      uint2 v4 = H2[r4 * 32 + sub], v5 = H2[r5 * 32 + sub];
      uint2 v6 = H2[r6 * 32 + sub], v7 = H2[r7 * 32 + sub];
      float2 p;
      p = bfpair(v0.x); a[0].x += p.x; a[0].y += p.y; p = bfpair(v0.y); a[0].z += p.x; a[0].w += p.y;
      p = bfpair(v1.x); a[1].x += p.x; a[1].y += p.y; p = bfpair(v1.y); a[1].z += p.x; a[1].w += p.y;
      p = bfpair(v2.x); a[2].x += p.x; a[2].y += p.y; p = bfpair(v2.y); a[2].z += p.x; a[2].w += p.y;
      p = bfpair(v3.x); a[3].x += p.x; a[3].y += p.y; p = bfpair(v3.y); a[3].z += p.x; a[3].w += p.y;
      p = bfpair(v4.x); a[4].x += p.x; a[4].y += p.y; p = bfpair(v4.y); a[4].z += p.x; a[4].w += p.y;
      p = bfpair(v5.x); a[5].x += p.x; a[5].y += p.y; p = bfpair(v5.y); a[5].z += p.x; a[5].w += p.y;
      p = bfpair(v6.x); a[6].x += p.x; a[6].y += p.y; p = bfpair(v6.y); a[6].z += p.x; a[6].w += p.y;
      p = bfpair(v7.x); a[7].x += p.x; a[7].y += p.y; p = bfpair(v7.y); a[7].z += p.x; a[7].w += p.y;
    }
    for (; j + 4 <= jm; j += 4) {
      int r0 = __shfl(idx, j, 32),     r1 = __shfl(idx, j + 1, 32);
      int r2 = __shfl(idx, j + 2, 32), r3 = __shfl(idx, j + 3, 32);
      uint2 v0 = H2[r0 * 32 + sub], v1 = H2[r1 * 32 + sub];
      uint2 v2 = H2[r2 * 32 + sub], v3 = H2[r3 * 32 + sub];
      float2 p;
      p = bfpair(v0.x); a[0].x += p.x; a[0].y += p.y; p = bfpair(v0.y); a[0].z += p.x; a[0].w += p.y;
      p = bfpair(v1.x); a[1].x += p.x; a[1].y += p.y; p = bfpair(v1.y); a[1].z += p.x; a[1].w += p.y;
      p = bfpair(v2.x); a[2].x += p.x; a[2].y += p.y; p = bfpair(v2.y); a[2].z += p.x; a[2].w += p.y;
      p = bfpair(v3.x); a[3].x += p.x; a[3].y += p.y; p = bfpair(v3.y); a[3].z += p.x; a[3].w += p.y;
    }
    for (; j < jm; ++j) {
      int r0 = __shfl(idx, j, 32);
      uint2 v0 = H2[r0 * 32 + sub];
      float2 p;
      p = bfpair(v0.x); a[0].x += p.x; a[0].y += p.y; p = bfpair(v0.y); a[0].z += p.x; a[0].w += p.y;
    }
  }
  float4 s;
  s.x = ((a[0].x + a[1].x) + (a[2].x + a[3].x)) + ((a[4].x + a[5].x) + (a[6].x + a[7].x));
  s.y = ((a[0].y + a[1].y) + (a[2].y + a[3].y)) + ((a[4].y + a[5].y) + (a[6].y + a[7].y));
  s.z = ((a[0].z + a[1].z) + (a[2].z + a[3].z)) + ((a[4].z + a[5].z) + (a[6].z + a[7].z));
  s.w = ((a[0].w + a[1].w) + (a[2].w + a[3].w)) + ((a[4].w + a[5].w) + (a[6].w + a[7].w));
  const float d = dis[node];
  float4 b = reinterpret_cast<const float4*>(bias)[sub];
  float ox = fmaxf(s.x * d + b.x, 0.f);
  float oy = fmaxf(s.y * d + b.y, 0.f);
  float oz = fmaxf(s.z * d + b.z, 0.f);
  float ow = fmaxf(s.w * d + b.w, 0.f);
  uint2 o;
  o.x = (unsigned int)f2bf(ox) | ((unsigned int)f2bf(oy) << 16);
  o.y = (unsigned int)f2bf(oz) | ((unsigned int)f2bf(ow) << 16);
  Z2[node * 32 + sub] = o;
}

// Hs2: float2 rows of 32 (64 f32 ch); row NN zero.
__global__ __launch_bounds__(256) void agg_f32_kernel(
    const float2* __restrict__ Hs2, const int* __restrict__ row_ptr,
    const int* __restrict__ csr, const float* __restrict__ dis,
    const float* __restrict__ bias, float2* __restrict__ out2, int n) {
  const int lane = threadIdx.x & 63;
  const int sub = lane & 31;
  int node = blockIdx.x * 8 + ((threadIdx.x >> 6) << 1) + (lane >> 5);
  if (node >= n) node = n - 1;

  const int s0 = row_ptr[node], s1 = row_ptr[node + 1];
  const int m = s1 - s0;
  const int mo = __shfl(m, lane ^ 32);
  const int mmax = m > mo ? m : mo;

  float2 a[8];
  a[0] = Hs2[node * 32 + sub];
#pragma unroll
  for (int i = 1; i < 8; ++i) a[i] = make_float2(0.f, 0.f);

  for (int e = 0; e < mmax; e += 32) {
    int idx = n;  // zero-row
    if (sub < m - e) idx = csr[s0 + e + sub];
    int jm = mmax - e;
    if (jm > 32) jm = 32;
    int j = 0;
    for (; j + 8 <= jm; j += 8) {
      int r0 = __shfl(idx, j, 32),     r1 = __shfl(idx, j + 1, 32);
      int r2 = __shfl(idx, j + 2, 32), r3 = __shfl(idx, j + 3, 32);
      int r4 = __shfl(idx, j + 4, 32), r5 = __shfl(idx, j + 5, 32);
      int r6 = __shfl(idx, j + 6, 32), r7 = __shfl(idx, j + 7, 32);
      float2 v0 = Hs2[r0 * 32 + sub], v1 = Hs2[r1 * 32 + sub];
      float2 v2 = Hs2[r2 * 32 + sub], v3 = Hs2[r3 * 32 + sub];
      float2 v4 = Hs2[r4 * 32 + sub], v5 = Hs2[r5 * 32 + sub];
      float2 v6 = Hs2[r6 * 32 + sub], v7 = Hs2[r7 * 32 + sub];
      a[0].x += v0.x; a[0].y += v0.y;  a[1].x += v1.x; a[1].y += v1.y;
      a[2].x += v2.x; a[2].y += v2.y;  a[3].x += v3.x; a[3].y += v3.y;
      a[4].x += v4.x; a[4].y += v4.y;  a[5].x += v5.x; a[5].y += v5.y;
      a[6].x += v6.x; a[6].y += v6.y;  a[7].x += v7.x; a[7].y += v7.y;
    }
    for (; j + 4 <= jm; j += 4) {
      int r0 = __shfl(idx, j, 32),     r1 = __shfl(idx, j + 1, 32);
      int r2 = __shfl(idx, j + 2, 32), r3 = __shfl(idx, j + 3, 32);
      float2 v0 = Hs2[r0 * 32 + sub], v1 = Hs2[r1 * 32 + sub];
      float2 v2 = Hs2[r2 * 32 + sub], v3 = Hs2[r3 * 32 + sub];
      a[0].x += v0.x; a[0].y += v0.y;  a[1].x += v1.x; a[1].y += v1.y;
      a[2].x += v2.x; a[2].y += v2.y;  a[3].x += v3.x; a[3].y += v3.y;
    }
    for (; j < jm; ++j) {
      float2 v = Hs2[__shfl(idx, j, 32) * 32 + sub];
      a[0].x += v.x; a[0].y += v.y;
    }
  }
  float sx = ((a[0].x + a[1].x) + (a[2].x + a[3].x)) + ((a[4].x + a[5].x) + (a[6].x + a[7].x));
  float sy = ((a[0].y + a[1].y) + (a[2].y + a[3].y)) + ((a[4].y + a[5].y) + (a[6].y + a[7].y));
  const float d = dis[node];
  float2 b = reinterpret_cast<const float2*>(bias)[sub];
  out2[node * 32 + sub] = make_float2(sx * d + b.x, sy * d + b.y);
}

// ---------------- launch ----------------

extern "C" void kernel_launch(void* const* d_in, const int* in_sizes, int n_in,
                              void* d_out, int out_size, void* d_ws, size_t ws_size,
                              hipStream_t stream) {
  const float* x  = (const float*)d_in[0];
  const int*   ei = (const int*)d_in[1];
  const float* W1 = (const float*)d_in[2];
  const float* b1 = (const float*)d_in[3];
  const float* W2 = (const float*)d_in[4];
  const float* b2 = (const float*)d_in[5];
  float* out = (float*)d_out;

  const int* row = ei;        // source nodes
  const int* col = ei + NE;   // destination nodes

  char* ws = (char*)d_ws;
  size_t off = 0;
  auto alloc = [&](size_t bytes) -> void* {
    off = (off + 255) & ~(size_t)255;
    void* p = ws + off;
    off += bytes;
    return p;
  };

  int* bcnt    = (int*)alloc((size_t)2 * NBK * sizeof(int));  // bcnt | bfill
  int* bfill   = bcnt + NBK;
  unsigned int* ebuf = (unsigned int*)alloc((size_t)NE * sizeof(unsigned int));
  int* row_ptr = (int*)alloc((size_t)(NN + 1) * sizeof(int));
  int* csr     = (int*)alloc((size_t)NE * sizeof(int));
  float* dis   = (float*)alloc((size_t)NN * sizeof(float));
  unsigned short* wt1h = (unsigned short*)alloc((size_t)(2 * 128 * 128 + 2 * 64 * 128) * 2);
  unsigned short* wt1l = wt1h + 128 * 128;
  unsigned short* wt2h = wt1l + 128 * 128;
  unsigned short* wt2l = wt2h + 64 * 128;
  // HT region: (NN+1) rows of 256B -- bf16[128] for layer 1, f32[64] for layer 2.
  // Row NN is the all-zero gather target for masked lanes (shared byte-identical).
  unsigned short* HT16 = (unsigned short*)alloc((size_t)(NN + 1) * 128 * 2);
  float* HT32 = (float*)HT16;
  unsigned short* Z1 = (unsigned short*)alloc((size_t)(NN + 1) * 128 * 2);

  wprep_kernel<<<97, 256, 0, stream>>>(W1, W2, wt1h, wt1l, wt2h, wt2l, bcnt,
                                       (unsigned int*)(HT16 + (size_t)NN * 128),
                                       (unsigned int*)(Z1 + (size_t)NN * 128));
  bucket_count_kernel<<<NE / CHUNK, 256, 0, stream>>>(col, bcnt);
  bucket_scatter_kernel<<<NE / CHUNK, 256, 0, stream>>>(row, col, bcnt, bfill, ebuf);
  bucket_build_kernel<<<NBK, 256, 0, stream>>>(ebuf, bcnt, row_ptr, dis, csr, NN);

  const int ga = (NN + 7) / 8;  // 6250 blocks, 2 nodes/wave

  // Layer 1: HT16 = bf16( dis .* (X @ W1) )  [NN][128], BM=64 -> 782 blocks
  gemm_mfma_kernel<64, 128, true, true><<<(NN + 63) / 64, 256, 0, stream>>>(
      x, wt1h, wt1l, dis, HT16, NN);
  agg_bf16_kernel<<<ga, 256, 0, stream>>>((const uint2*)HT16, row_ptr, csr, dis, b1,
                                          (uint2*)Z1, NN);

  // Layer 2: HT32 = dis .* (Z1 @ W2)  [NN][64], BM=64 -> 782 blocks
  gemm_mfma_kernel<64, 64, false, false><<<(NN + 63) / 64, 256, 0, stream>>>(
      Z1, wt2h, wt2l, dis, HT32, NN);
  agg_f32_kernel<<<ga, 256, 0, stream>>>((const float2*)HT32, row_ptr, csr, dis, b2,
                                         (float2*)out, NN);
}